// Round 8
// baseline (26533.661 us; speedup 1.0000x reference)
//
#include <hip/hip_runtime.h>
#include <hip/hip_bf16.h>
#include <stdint.h>

typedef __attribute__((ext_vector_type(8))) short bf16x8;
typedef __attribute__((ext_vector_type(4))) float f32x4;
typedef unsigned long long ull;

// ---- problem constants ----
#define N_SAMP 128
#define T_STEPS 512
#define RSLOTS2 64
#define GL 100    // legacy glds pad
#define GS 772    // k_run2 glds row stride (floats), 772%32=4 -> bank rotate

// ---- ws layout (new persistent path) ----
#define WT_OFF    0u           // bf16 weights, 3538944 B
#define GC_OFF    3538944u     // gconst fp32, 1179648 B
#define PROG_OFF  4718592u     // 24 counters, stride 64B -> 4096 B
#define HIST2_OFF 4722688u     // hist[2][64][128][256] bf16 = 8388608 B
#define CB2_OFF   13111296u    // chars bf16 fragment tiles [8][512][4096] = 33554432 B
#define NEED_NEW  46665728ull
// legacy fallback layout (exclusive)
#define RING_OFF  4718592u

__device__ __forceinline__ ushort f2bf(float f) {
    uint32_t u = __float_as_uint(f);
    uint32_t r = u + 0x7FFFu + ((u >> 16) & 1u);
    return (ushort)(r >> 16);
}
__device__ __forceinline__ float sigmoidf_(float x) { return 1.0f / (1.0f + __expf(-x)); }

__device__ __forceinline__ void llc_load16(uint4& dst, const void* p) {
    asm volatile("global_load_dwordx4 %0, %1, off sc0 sc1" : "=&v"(dst) : "v"(p) : "memory");
}
// 8B write-through store (16B aggregates are not supported as asm INPUTS -> use 2x8B)
__device__ __forceinline__ void llc_store8(void* p, ull v) {
    asm volatile("global_store_dwordx2 %0, %1, off sc0 sc1" :: "v"(p), "v"(v) : "memory");
}
__device__ __forceinline__ void drain_vmem() {
    asm volatile("s_waitcnt vmcnt(0)" ::: "memory");
}

// ---------------- phase 0a: weight prep (fp32 -> bf16, [col][k], gate-cols permuted)
__global__ void k_prep(const float* __restrict__ w0, const float* __restrict__ w1,
                       const float* __restrict__ w2, ushort* __restrict__ wt) {
    int idx = blockIdx.x * 256 + threadIdx.x;
    if (idx >= 1769472) return;
    int e, Ks, cols; const float* W;
    if (idx < 393216)      { e = idx;          Ks = 512;  cols = 1024; W = w0; }
    else if (idx < 983040) { e = idx - 393216; Ks = 768;  cols = 1280; W = w1; }
    else                   { e = idx - 983040; Ks = 1024; cols = 1536; W = w2; }
    int c = e / Ks, k = e % Ks;
    int b = c / 96, cc = c % 96, g = cc >> 5, d32 = cc & 31;
    int j = g * 256 + b * 32 + d32;
    int scol = (k < 256) ? k : (512 + k);
    wt[idx] = f2bf(W[(size_t)j * cols + scol]);
}

// ---------------- phase 0b: gconst
__global__ void k_gconst(const float* __restrict__ w0, const float* __restrict__ w1, const float* __restrict__ w2,
                         const float* __restrict__ bih0, const float* __restrict__ bih1, const float* __restrict__ bih2,
                         const float* __restrict__ bhh0, const float* __restrict__ bhh1, const float* __restrict__ bhh2,
                         const float* __restrict__ sent, const float* __restrict__ ctx,
                         float* __restrict__ gc) {
    int idx = blockIdx.x * 256 + threadIdx.x;
    if (idx >= 3 * 768 * 128) return;
    int n = idx & 127;
    int scc = idx >> 7;
    int c = scc % 768, s = scc / 768;
    const float* W   = (s == 0) ? w0 : ((s == 1) ? w1 : w2);
    const float* bih = (s == 0) ? bih0 : ((s == 1) ? bih1 : bih2);
    const float* bhh = (s == 0) ? bhh0 : ((s == 1) ? bhh1 : bhh2);
    int cols = 1024 + 256 * s;
    int b = c / 96, cc = c % 96, g = cc >> 5, d32 = cc & 31;
    int j = g * 256 + b * 32 + d32;
    float acc = bih[j] + ((g < 2) ? bhh[j] : 0.0f);
    const float4* wr4 = (const float4*)(W + (size_t)j * cols + 256);
    const float4* sn4 = (const float4*)(sent + (size_t)n * 256);
    const float4* cx4 = (const float4*)(ctx + (size_t)n * 256);
    #pragma unroll 4
    for (int k = 0; k < 64; k++) {
        float4 wv = wr4[k], sv = sn4[k];
        acc += wv.x * sv.x + wv.y * sv.y + wv.z * sv.z + wv.w * sv.w;
    }
    #pragma unroll 4
    for (int k = 0; k < 64; k++) {
        float4 wv = wr4[64 + k], cv = cx4[k];
        acc += wv.x * cv.x + wv.y * cv.y + wv.z * cv.z + wv.w * cv.w;
    }
    gc[(size_t)(s * 128 + n) * 768 + c] = acc;
}

// ---------------- phase 0c: chars -> bf16 fragment tiles cb[g][t][4096]
__global__ void k_cprep(const float* __restrict__ chars, ushort* __restrict__ cb) {
    int idx = blockIdx.x * 256 + threadIdx.x;
    if (idx >= 2097152) return;
    int q = idx & 511;
    int gt = idx >> 9;
    int t = gt & 511, g = gt >> 9;
    int r = q >> 5, ko = (q & 31) << 3;
    int n = g * 16 + r;
    const float* src = chars + ((size_t)n * T_STEPS + t) * 256 + ko;
    float4 f0 = *(const float4*)src;
    float4 f1 = *(const float4*)(src + 4);
    union { ushort u[8]; uint4 v; } pk;
    pk.u[0] = f2bf(f0.x); pk.u[1] = f2bf(f0.y); pk.u[2] = f2bf(f0.z); pk.u[3] = f2bf(f0.w);
    pk.u[4] = f2bf(f1.x); pk.u[5] = f2bf(f1.y); pk.u[6] = f2bf(f1.z); pk.u[7] = f2bf(f1.w);
    int pos = (ko >> 5) * 512 + (r + 16 * ((ko >> 3) & 3)) * 8;
    *(uint4*)(cb + (size_t)gt * 4096 + pos) = pk.v;
}

// ---------------- persistent mega-WG kernel: 24 WGs = 3 stages x 8 groups, 512 thr (8 waves)
// Wave w owns cols [w*96, w*96+96). Self-recurrence entirely in LDS.
__global__ void __launch_bounds__(512) k_run2(
    const ushort* __restrict__ cb, const ushort* __restrict__ wt,
    const float* __restrict__ gc, ushort* __restrict__ hist, int* __restrict__ prog,
    const float* __restrict__ bhh0, const float* __restrict__ bhh1, const float* __restrict__ bhh2,
    const float* __restrict__ hw0, const float* __restrict__ hw1, const float* __restrict__ hw2,
    const float* __restrict__ hb0, const float* __restrict__ hb1, const float* __restrict__ hb2,
    float* __restrict__ out) {
    __shared__ ushort Alds[16384];       // [16 x Ks] fragment layout (<=32KB)
    __shared__ float  glds[16 * GS];     // gate preacts [sample][768] padded

    int bid = blockIdx.x;
    int s = bid >> 3;
    int g = bid & 7;
    int Ks = 512 + 256 * s;
    const ushort* wts = wt + ((s == 0) ? 0 : ((s == 1) ? 393216 : 983040));
    int tid = threadIdx.x;
    int w = tid >> 6, lane = tid & 63;
    int ksO = 8 + 8 * s;          // own-h k-iter base; OWNK = ksO*32
    const float* bhh = (s == 0) ? bhh0 : ((s == 1) ? bhh1 : bhh2);
    const float* hw  = (s == 0) ? hw0  : ((s == 1) ? hw1  : hw2);
    const float* hb  = (s == 0) ? hb0  : ((s == 1) ? hb1  : hb2);

    // B pointers, 6 col-blocks of 16 per wave
    const ushort* bp0 = wts + (size_t)(w * 96 + (lane & 15)) * Ks + ((lane >> 4) << 3);
    const ushort* bp1 = bp0 + (size_t)16 * Ks;
    const ushort* bp2 = bp0 + (size_t)32 * Ks;
    const ushort* bp3 = bp0 + (size_t)48 * Ks;
    const ushort* bp4 = bp0 + (size_t)64 * Ks;
    const ushort* bp5 = bp0 + (size_t)80 * Ks;

    // zero own-h region (h(-1)=0): 512 thr x 16B = 8KB
    {
        int r = tid >> 5, ko = (tid & 31) << 3;
        int k = ksO * 32 + ko;
        int pos = (k >> 5) * 512 + (r + 16 * ((ko >> 3) & 3)) * 8;
        uint4 z = {0, 0, 0, 0};
        *(uint4*)(Alds + pos) = z;
    }
    __syncthreads();

    int* pprog0 = prog + (0 * 8 + g) * 16;
    int* pprog1 = prog + (1 * 8 + g) * 16;
    int* pprog2 = prog + (2 * 8 + g) * 16;
    int* pself  = prog + (s * 8 + g) * 16;

    for (int t = 0; t < T_STEPS; ++t) {
        // ---- waits (2 predicated lanes, parallel)
        if (tid < 2) {
            int* p = nullptr; int want = 0;
            if (tid == 0) {
                if (s >= 1)              { p = pprog0; want = t + 1; }           // pw data
                else if (t >= RSLOTS2)   { p = pprog2; want = t - RSLOTS2 + 1; } // pw backpressure on iph
            } else {
                if (s == 2)                   { p = pprog1; want = t + 1; }           // pph data
                else if (s == 1 && t >= RSLOTS2) { p = pprog2; want = t - RSLOTS2 + 1; } // pph backpressure
            }
            if (p) {
                while (__hip_atomic_load(p, __ATOMIC_RELAXED, __HIP_MEMORY_SCOPE_AGENT) < want) {}
            }
        }
        // ---- char stage: 8KB pre-tiled copy
        {
            const uint4* src = (const uint4*)(cb + ((size_t)(g * 512 + t)) * 4096);
            ((uint4*)Alds)[tid] = src[tid];
        }
        __syncthreads();   // B1: chars staged, waits observed

        // ---- upstream h loads (LLC), in flight during M1
        uint4 hu0, hu1;
        if (s >= 1) {
            int r = tid >> 5, ko = (tid & 31) << 3;
            int n = g * 16 + r;
            llc_load16(hu0, hist + (((size_t)0 * RSLOTS2 + (t & 63)) * 128 + n) * 256 + ko);
            if (s == 2)
                llc_load16(hu1, hist + (((size_t)1 * RSLOTS2 + (t & 63)) * 128 + n) * 256 + ko);
        }

        // ---- MFMA
        f32x4 acc0 = {0,0,0,0}, acc1 = {0,0,0,0}, acc2 = {0,0,0,0};
        f32x4 acc3 = {0,0,0,0}, acc4 = {0,0,0,0}, acc5 = {0,0,0,0};
#define MFMA_K(KS)                                                                              \
        {   bf16x8 a = *(const bf16x8*)(Alds + (KS) * 512 + lane * 8);                          \
            acc0 = __builtin_amdgcn_mfma_f32_16x16x32_bf16(a, *(const bf16x8*)(bp0 + (size_t)(KS) * 32), acc0, 0, 0, 0); \
            acc1 = __builtin_amdgcn_mfma_f32_16x16x32_bf16(a, *(const bf16x8*)(bp1 + (size_t)(KS) * 32), acc1, 0, 0, 0); \
            acc2 = __builtin_amdgcn_mfma_f32_16x16x32_bf16(a, *(const bf16x8*)(bp2 + (size_t)(KS) * 32), acc2, 0, 0, 0); \
            acc3 = __builtin_amdgcn_mfma_f32_16x16x32_bf16(a, *(const bf16x8*)(bp3 + (size_t)(KS) * 32), acc3, 0, 0, 0); \
            acc4 = __builtin_amdgcn_mfma_f32_16x16x32_bf16(a, *(const bf16x8*)(bp4 + (size_t)(KS) * 32), acc4, 0, 0, 0); \
            acc5 = __builtin_amdgcn_mfma_f32_16x16x32_bf16(a, *(const bf16x8*)(bp5 + (size_t)(KS) * 32), acc5, 0, 0, 0); }

        // M1: char (ks 0..7) + own-h (ks ksO..ksO+7) — both already in LDS
        #pragma unroll
        for (int ks = 0; ks < 8; ks++) MFMA_K(ks)
        #pragma unroll
        for (int j = 0; j < 8; j++) MFMA_K(ksO + j)

        if (s >= 1) {
            drain_vmem();
            __builtin_amdgcn_sched_barrier(0);
            {
                int r = tid >> 5, ko = (tid & 31) << 3;
                int pos1 = ((256 + ko) >> 5) * 512 + (r + 16 * ((ko >> 3) & 3)) * 8;
                *(uint4*)(Alds + pos1) = hu0;
                if (s == 2) {
                    int pos2 = ((512 + ko) >> 5) * 512 + (r + 16 * ((ko >> 3) & 3)) * 8;
                    *(uint4*)(Alds + pos2) = hu1;
                }
            }
            __syncthreads();   // B2: upstream staged
            // M2: upstream k range (s==1: ks 8..15; s==2: ks 8..23)
            #pragma unroll 8
            for (int ks = 8; ks < ksO; ks++) MFMA_K(ks)
        }
#undef MFMA_K

        // ---- acc -> glds
        {
            int rbase = (lane >> 4) * 4;
            int c0 = w * 96 + (lane & 15);
            #pragma unroll
            for (int q = 0; q < 4; q++) {
                glds[(rbase + q) * GS + c0]      = acc0[q];
                glds[(rbase + q) * GS + c0 + 16] = acc1[q];
                glds[(rbase + q) * GS + c0 + 32] = acc2[q];
                glds[(rbase + q) * GS + c0 + 48] = acc3[q];
                glds[(rbase + q) * GS + c0 + 64] = acc4[q];
                glds[(rbase + q) * GS + c0 + 80] = acc5[q];
            }
        }
        __syncthreads();   // B3: gates ready

        // ---- gates: thread -> sample sl, 8 h-dims [d0, d0+8)
        int sl = tid >> 5;
        int d0 = (tid & 31) << 3;
        int n  = g * 16 + sl;
        int bb96 = (d0 >> 5) * 96, d32 = d0 & 31;
        const float* grow = glds + sl * GS + bb96;
        const float* gcp  = gc + (size_t)(s * 128 + n) * 768 + bb96;
        float hv[8];
        union { ushort u[8]; uint4 v4; ull v2[2]; } hpk;
        #pragma unroll
        for (int dd = 0; dd < 8; dd++) {
            int di = d32 + dd;
            int d  = d0 + dd;
            float rp = grow[di]      + gcp[di];
            float zp = grow[32 + di] + gcp[32 + di];
            float np = grow[64 + di] + gcp[64 + di];
            float rg = sigmoidf_(rp);
            float zg = sigmoidf_(zp);
            float ng = tanhf(np + rg * bhh[512 + d]);
            float h  = (1.0f - zg) * ng;
            hv[dd] = h;
            hpk.u[dd] = f2bf(h);
        }
        // own-h into Alds fragment slot for next step (read after B4+B1)
        {
            int k = ksO * 32 + d0;
            int pos = (k >> 5) * 512 + (sl + 16 * ((d0 >> 3) & 3)) * 8;
            *(uint4*)(Alds + pos) = hpk.v4;
        }
        // ring publish (pw, pph) — 2x8B write-through stores
        if (s <= 1) {
            ushort* dst = hist + (((size_t)s * RSLOTS2 + (t & 63)) * 128 + n) * 256 + d0;
            llc_store8(dst,     hpk.v2[0]);
            llc_store8(dst + 4, hpk.v2[1]);
            drain_vmem();   // per-wave drain of write-through stores
        }
        __syncthreads();   // B4: Alds own-h visible, ring data at LLC
        if (tid == 0) {
            __hip_atomic_fetch_add(pself, 1, __ATOMIC_RELAXED, __HIP_MEMORY_SCOPE_AGENT);
        }
        // ---- head projection (single writer per sample, off critical path)
        {
            float y0 = 0.f, y1 = 0.f;
            #pragma unroll
            for (int dd = 0; dd < 8; dd++) {
                int d = d0 + dd;
                y0 += hv[dd] * hw[d];
                y1 += hv[dd] * hw[256 + d];
            }
            y0 += __shfl_xor(y0, 1);  y1 += __shfl_xor(y1, 1);
            y0 += __shfl_xor(y0, 2);  y1 += __shfl_xor(y1, 2);
            y0 += __shfl_xor(y0, 4);  y1 += __shfl_xor(y1, 4);
            y0 += __shfl_xor(y0, 8);  y1 += __shfl_xor(y1, 8);
            y0 += __shfl_xor(y0, 16); y1 += __shfl_xor(y1, 16);
            if ((tid & 31) == 0) {
                y0 += hb[0]; y1 += hb[1];
                int bi = n >> 3, ci = n & 7;
                out[(size_t)s * 131072 + (size_t)((bi * 2 + 0) * 8 + ci) * 512 + t] = y0;
                out[(size_t)s * 131072 + (size_t)((bi * 2 + 1) * 8 + ci) * 512 + t] = y1;
            }
        }
    }
}

// ---------------- legacy pipelined step kernel (fallback when ws is small)
__global__ void __launch_bounds__(128) k_step(
    const float* __restrict__ chars, const ushort* __restrict__ wt,
    const float* __restrict__ gc, ushort* __restrict__ ring,
    const float* __restrict__ bhh0, const float* __restrict__ bhh1, const float* __restrict__ bhh2,
    const float* __restrict__ hw0, const float* __restrict__ hw1, const float* __restrict__ hw2,
    const float* __restrict__ hb0, const float* __restrict__ hb1, const float* __restrict__ hb2,
    float* __restrict__ out, int stepi) {
    __shared__ ushort Alds[16384];
    __shared__ float  glds[16 * GL];

    int bx = blockIdx.x;
    int s  = bx >> 6;
    int r2 = bx & 63;
    int mt = r2 >> 3;
    int nb = r2 & 7;
    int t  = stepi - s;
    if (t < 0 || t >= T_STEPS) return;

    int Ks = 512 + 256 * s;
    const ushort* wts = wt + ((s == 0) ? 0 : ((s == 1) ? 393216 : 983040));
    int tid = threadIdx.x;

    #pragma unroll
    for (int i = 0; i < 4; i++) {
        int q  = tid + 128 * i;
        int r  = q >> 5;
        int ko = (q & 31) << 3;
        int n  = mt * 16 + r;
        const float* src = chars + ((size_t)n * T_STEPS + t) * 256 + ko;
        float4 f0 = *(const float4*)src;
        float4 f1 = *(const float4*)(src + 4);
        union { ushort u[8]; uint4 v; } pk;
        pk.u[0] = f2bf(f0.x); pk.u[1] = f2bf(f0.y); pk.u[2] = f2bf(f0.z); pk.u[3] = f2bf(f0.w);
        pk.u[4] = f2bf(f1.x); pk.u[5] = f2bf(f1.y); pk.u[6] = f2bf(f1.z); pk.u[7] = f2bf(f1.w);
        int pos = (ko >> 5) * 512 + (r + 16 * ((ko >> 3) & 3)) * 8;
        *(uint4*)(Alds + pos) = pk.v;
    }
    int nparts = s + 1;
    for (int p = 0; p < nparts; p++) {
        int slot = (p == s) ? ((t - 1) & 3) : (t & 3);
        const ushort* hsrc = ring + ((size_t)p * 4 + slot) * (128 * 256);
        #pragma unroll
        for (int i = 0; i < 4; i++) {
            int q  = tid + 128 * i;
            int r  = q >> 5;
            int ko = (q & 31) << 3;
            int n  = mt * 16 + r;
            uint4 v = *(const uint4*)(hsrc + (size_t)n * 256 + ko);
            int kg  = 256 + p * 256 + ko;
            int pos = (kg >> 5) * 512 + (r + 16 * ((kg >> 3) & 3)) * 8;
            *(uint4*)(Alds + pos) = v;
        }
    }
    __syncthreads();

    int w = tid >> 6, lane = tid & 63;
    int cbcol = nb * 96 + w * 48;
    f32x4 acc0 = {0,0,0,0}, acc1 = {0,0,0,0}, acc2 = {0,0,0,0};
    const ushort* bp0 = wts + (size_t)(cbcol + (lane & 15)) * Ks + ((lane >> 4) << 3);
    const ushort* bp1 = bp0 + 16 * (size_t)Ks;
    const ushort* bp2 = bp0 + 32 * (size_t)Ks;
    const ushort* ap  = Alds + lane * 8;
    int nk = Ks >> 5;
    #pragma unroll 8
    for (int ks = 0; ks < nk; ks++) {
        bf16x8 a  = *(const bf16x8*)(ap + ks * 512);
        bf16x8 b0 = *(const bf16x8*)(bp0 + ks * 32);
        bf16x8 b1 = *(const bf16x8*)(bp1 + ks * 32);
        bf16x8 b2 = *(const bf16x8*)(bp2 + ks * 32);
        acc0 = __builtin_amdgcn_mfma_f32_16x16x32_bf16(a, b0, acc0, 0, 0, 0);
        acc1 = __builtin_amdgcn_mfma_f32_16x16x32_bf16(a, b1, acc1, 0, 0, 0);
        acc2 = __builtin_amdgcn_mfma_f32_16x16x32_bf16(a, b2, acc2, 0, 0, 0);
    }
    {
        int rbase = (lane >> 4) * 4;
        int c0 = w * 48 + (lane & 15);
        #pragma unroll
        for (int q = 0; q < 4; q++) {
            glds[(rbase + q) * GL + c0]      = acc0[q];
            glds[(rbase + q) * GL + c0 + 16] = acc1[q];
            glds[(rbase + q) * GL + c0 + 32] = acc2[q];
        }
    }
    __syncthreads();

    {
        int sl = tid >> 3;
        int d0 = (tid & 7) * 4;
        int n  = mt * 16 + sl;
        const float* bhh = (s == 0) ? bhh0 : ((s == 1) ? bhh1 : bhh2);
        const float* hw  = (s == 0) ? hw0  : ((s == 1) ? hw1  : hw2);
        const float* hb  = (s == 0) ? hb0  : ((s == 1) ? hb1  : hb2);
        const float* gcp = gc + (size_t)(s * 128 + n) * 768 + nb * 96;
        float y0 = 0.f, y1 = 0.f;
        union { ushort u[4]; uint2 v; } hpk;
        #pragma unroll
        for (int dd = 0; dd < 4; dd++) {
            int d32 = d0 + dd;
            int d   = nb * 32 + d32;
            float rp = glds[sl * GL + d32]      + gcp[d32];
            float zp = glds[sl * GL + 32 + d32] + gcp[32 + d32];
            float np = glds[sl * GL + 64 + d32] + gcp[64 + d32];
            float rg = sigmoidf_(rp);
            float zg = sigmoidf_(zp);
            float ng = tanhf(np + rg * bhh[512 + d]);
            float h  = (1.0f - zg) * ng;
            hpk.u[dd] = f2bf(h);
            y0 += h * hw[d];
            y1 += h * hw[256 + d];
        }
        *(uint2*)(ring + (((size_t)s * 4 + (t & 3)) * 128 + n) * 256 + nb * 32 + d0) = hpk.v;
        y0 += __shfl_xor(y0, 1); y0 += __shfl_xor(y0, 2); y0 += __shfl_xor(y0, 4);
        y1 += __shfl_xor(y1, 1); y1 += __shfl_xor(y1, 2); y1 += __shfl_xor(y1, 4);
        if ((tid & 7) == 0) {
            if (nb == 0) { y0 += hb[0]; y1 += hb[1]; }
            int bi = n >> 3, ci = n & 7;
            atomicAdd(out + (size_t)s * 131072 + (size_t)((bi * 2 + 0) * 8 + ci) * 512 + t, y0);
            atomicAdd(out + (size_t)s * 131072 + (size_t)((bi * 2 + 1) * 8 + ci) * 512 + t, y1);
        }
    }
}

extern "C" void kernel_launch(void* const* d_in, const int* in_sizes, int n_in,
                              void* d_out, int out_size, void* d_ws, size_t ws_size,
                              hipStream_t stream) {
    const float* chars = (const float*)d_in[0];
    const float* sent  = (const float*)d_in[1];
    const float* ctx   = (const float*)d_in[2];
    const float* w0    = (const float*)d_in[3];
    const float* bih0  = (const float*)d_in[4];
    const float* bhh0  = (const float*)d_in[5];
    const float* w1    = (const float*)d_in[6];
    const float* bih1  = (const float*)d_in[7];
    const float* bhh1  = (const float*)d_in[8];
    const float* w2    = (const float*)d_in[9];
    const float* bih2  = (const float*)d_in[10];
    const float* bhh2  = (const float*)d_in[11];
    const float* hw0   = (const float*)d_in[12];
    const float* hb0   = (const float*)d_in[13];
    const float* hw1   = (const float*)d_in[14];
    const float* hb1   = (const float*)d_in[15];
    const float* hw2   = (const float*)d_in[16];
    const float* hb2   = (const float*)d_in[17];

    char* ws = (char*)d_ws;
    ushort* wt  = (ushort*)(ws + WT_OFF);
    float*  gcb = (float*)(ws + GC_OFF);
    float*  out = (float*)d_out;

    hipMemsetAsync(d_out, 0, (size_t)out_size * sizeof(float), stream);
    k_prep<<<6912, 256, 0, stream>>>(w0, w1, w2, wt);
    k_gconst<<<1152, 256, 0, stream>>>(w0, w1, w2, bih0, bih1, bih2,
                                       bhh0, bhh1, bhh2, sent, ctx, gcb);

    if (ws_size >= NEED_NEW) {
        int*    prg  = (int*)(ws + PROG_OFF);
        ushort* hist = (ushort*)(ws + HIST2_OFF);
        ushort* cbuf = (ushort*)(ws + CB2_OFF);
        hipMemsetAsync(ws + PROG_OFF, 0, 4096, stream);
        k_cprep<<<8192, 256, 0, stream>>>(chars, cbuf);
        k_run2<<<24, 512, 0, stream>>>(cbuf, wt, gcb, hist, prg,
                                       bhh0, bhh1, bhh2, hw0, hw1, hw2,
                                       hb0, hb1, hb2, out);
    } else {
        ushort* ring = (ushort*)(ws + RING_OFF);
        hipMemsetAsync(ring, 0, (size_t)3 * 4 * 128 * 256 * 2, stream);
        for (int i = 0; i < T_STEPS + 2; i++) {
            k_step<<<192, 128, 0, stream>>>(chars, wt, gcb, ring,
                                            bhh0, bhh1, bhh2, hw0, hw1, hw2,
                                            hb0, hb1, hb2, out, i);
        }
    }
}

// Round 9
// 7112.550 us; speedup vs baseline: 3.7305x; 3.7305x over previous
//
#include <hip/hip_runtime.h>
#include <hip/hip_bf16.h>
#include <stdint.h>

typedef __attribute__((ext_vector_type(8))) short bf16x8;
typedef __attribute__((ext_vector_type(4))) float f32x4;
typedef unsigned long long ull;

// ---- problem constants ----
#define T_STEPS 512
#define RS3 32          // hist ring slots (new path)
#define GL 100          // legacy glds pad

// ---- ws layout (new persistent path) ----
#define WT_OFF    0u           // bf16 weights, 3538944 B (fragment-ordered wt2)
#define GC_OFF    3538944u     // gcf fp32 fragment-ordered, 1179648 B
#define PROG_OFF  4718592u     // 24 counters, stride 64B
#define HIST3_OFF 4722688u     // hist[3][32][8][4096] ushort = 6291456 B
#define CB_OFF    13111296u    // chars bf16 fragment tiles [8][512][4096] = 33554432 B
#define NEED_NEW  46665728ull
// legacy fallback layout (exclusive with new path)
#define RING_OFF  4718592u

__device__ __forceinline__ ushort f2bf(float f) {
    uint32_t u = __float_as_uint(f);
    uint32_t r = u + 0x7FFFu + ((u >> 16) & 1u);
    return (ushort)(r >> 16);
}
__device__ __forceinline__ float sigmoidf_(float x) { return 1.0f / (1.0f + __expf(-x)); }

// ordered VMEM primitives (all counted loads are asm so vmcnt(N) semantics hold)
__device__ __forceinline__ void gld16(bf16x8& d, const void* p) {        // plain cached 16B
    asm volatile("global_load_dwordx4 %0, %1, off" : "=&v"(d) : "v"(p) : "memory");
}
__device__ __forceinline__ void gld16c(bf16x8& d, const void* p) {       // LLC-coherent 16B
    asm volatile("global_load_dwordx4 %0, %1, off sc0 sc1" : "=&v"(d) : "v"(p) : "memory");
}
__device__ __forceinline__ void gld16u(uint4& d, const void* p) {        // plain cached 16B (uint4)
    asm volatile("global_load_dwordx4 %0, %1, off" : "=&v"(d) : "v"(p) : "memory");
}
__device__ __forceinline__ void llc_store8(void* p, ull v) {             // write-through 8B
    asm volatile("global_store_dwordx2 %0, %1, off sc0 sc1" :: "v"(p), "v"(v) : "memory");
}
#define VWAIT(N) { asm volatile("s_waitcnt vmcnt(" #N ")" ::: "memory"); __builtin_amdgcn_sched_barrier(0); }
__device__ __forceinline__ void drain_vmem() {
    asm volatile("s_waitcnt vmcnt(0)" ::: "memory");
}

// ---------------- NEW phase 0a: weights -> bf16, MFMA-fragment order (wt2)
// wt2 per (s,j): (s+2) chunks of 24576 ushorts; chunk = [ct(6)][ks(8)][lane(64)][8]
__global__ void k_prep2(const float* __restrict__ w0, const float* __restrict__ w1,
                        const float* __restrict__ w2, ushort* __restrict__ wt2) {
    int idx = blockIdx.x * 256 + threadIdx.x;
    if (idx >= 1769472) return;
    int e, Ks, cols, s; const float* W;
    if (idx < 393216)      { e = idx;          Ks = 512;  cols = 1024; W = w0; s = 0; }
    else if (idx < 983040) { e = idx - 393216; Ks = 768;  cols = 1280; W = w1; s = 1; }
    else                   { e = idx - 983040; Ks = 1024; cols = 1536; W = w2; s = 2; }
    int c = e / Ks, k = e % Ks;
    int j = c / 96, cc = c % 96;
    int g = cc >> 5, d32 = cc & 31;
    int ct = cc >> 4, cl = cc & 15;
    int srcrow = g * 256 + j * 32 + d32;
    int scol = (k < 256) ? k : (512 + k);
    int kc = k >> 8, kl = k & 255, ks = kl >> 5, ko = kl & 31;
    int lane = ((ko >> 3) << 4) | cl, elem = ko & 7;
    size_t sbase = (s == 0) ? 0u : ((s == 1) ? 393216u : 983040u);
    size_t dst = sbase + (size_t)j * (s + 2) * 24576 +
                 ((size_t)(kc * 6 + ct) * 8 + ks) * 512 + lane * 8 + elem;
    wt2[dst] = f2bf(W[(size_t)srcrow * cols + scol]);
}

// ---------------- NEW phase 0b: gconst in C-fragment order (gcf)
// gcf idx = ((((s*8+j)*6+ct)*8+rt)*64+lane)*4+q
__global__ void k_gconst2(const float* __restrict__ w0, const float* __restrict__ w1, const float* __restrict__ w2,
                          const float* __restrict__ bih0, const float* __restrict__ bih1, const float* __restrict__ bih2,
                          const float* __restrict__ bhh0, const float* __restrict__ bhh1, const float* __restrict__ bhh2,
                          const float* __restrict__ sent, const float* __restrict__ ctx,
                          float* __restrict__ gcf) {
    int idx = blockIdx.x * 256 + threadIdx.x;
    if (idx >= 294912) return;
    int q = idx & 3; int r1 = idx >> 2;
    int lane = r1 & 63; int r2 = r1 >> 6;
    int rt = r2 & 7; int r3 = r2 >> 3;
    int ct = r3 % 6; int sj = r3 / 6;
    int s = sj >> 3, j = sj & 7;
    const float* W   = (s == 0) ? w0 : ((s == 1) ? w1 : w2);
    const float* bih = (s == 0) ? bih0 : ((s == 1) ? bih1 : bih2);
    const float* bhh = (s == 0) ? bhh0 : ((s == 1) ? bhh1 : bhh2);
    int cols = 1024 + 256 * s;
    int cc = ct * 16 + (lane & 15);
    int g = cc >> 5, d32 = cc & 31;
    int jr = g * 256 + j * 32 + d32;
    int n = rt * 16 + ((lane >> 4) << 2) + q;
    float acc = bih[jr] + ((g < 2) ? bhh[jr] : 0.0f);
    const float4* wr4 = (const float4*)(W + (size_t)jr * cols + 256);
    const float4* sn4 = (const float4*)(sent + (size_t)n * 256);
    const float4* cx4 = (const float4*)(ctx + (size_t)n * 256);
    #pragma unroll 4
    for (int k = 0; k < 64; k++) {
        float4 wv = wr4[k], sv = sn4[k];
        acc += wv.x * sv.x + wv.y * sv.y + wv.z * sv.z + wv.w * sv.w;
    }
    #pragma unroll 4
    for (int k = 0; k < 64; k++) {
        float4 wv = wr4[64 + k], cv = cx4[k];
        acc += wv.x * cv.x + wv.y * cv.y + wv.z * cv.z + wv.w * cv.w;
    }
    gcf[idx] = acc;
}

// ---------------- phase 0c: chars -> bf16 fragment tiles cb[rt][t][4096] (unchanged)
__global__ void k_cprep(const float* __restrict__ chars, ushort* __restrict__ cb) {
    int idx = blockIdx.x * 256 + threadIdx.x;
    if (idx >= 2097152) return;
    int q = idx & 511;
    int gt = idx >> 9;
    int t = gt & 511, g = gt >> 9;
    int r = q >> 5, ko = (q & 31) << 3;
    int n = g * 16 + r;
    const float* src = chars + ((size_t)n * T_STEPS + t) * 256 + ko;
    float4 f0 = *(const float4*)src;
    float4 f1 = *(const float4*)(src + 4);
    union { ushort u[8]; uint4 v; } pk;
    pk.u[0] = f2bf(f0.x); pk.u[1] = f2bf(f0.y); pk.u[2] = f2bf(f0.z); pk.u[3] = f2bf(f0.w);
    pk.u[4] = f2bf(f1.x); pk.u[5] = f2bf(f1.y); pk.u[6] = f2bf(f1.z); pk.u[7] = f2bf(f1.w);
    int pos = (ko >> 5) * 512 + (r + 16 * ((ko >> 3) & 3)) * 8;
    *(uint4*)(cb + (size_t)gt * 4096 + pos) = pk.v;
}

// ---------------- k_run3: 24 WGs = 3 stages x 8 col-chunks, 512 thr, M=128
__global__ void __launch_bounds__(512) k_run3(
    const ushort* __restrict__ cb, const ushort* __restrict__ wt2,
    const float* __restrict__ gcf, ushort* __restrict__ hist, int* __restrict__ prog,
    const float* __restrict__ bhh0, const float* __restrict__ bhh1, const float* __restrict__ bhh2,
    const float* __restrict__ hw0, const float* __restrict__ hw1, const float* __restrict__ hw2,
    const float* __restrict__ hb0, const float* __restrict__ hb1, const float* __restrict__ hb2,
    float* __restrict__ out) {
    __shared__ ushort Blds[73728];   // 3 x 24576 ushorts = 144KB
    __shared__ ushort hlds[4096];    // [sample(128)][d32(32)] bf16 = 8KB

    int bid = blockIdx.x;
    int s = bid >> 3, j = bid & 7;
    int tid = threadIdx.x;
    int w = tid >> 6, lane = tid & 63, la = lane & 15;
    const float* bhh = (s == 0) ? bhh0 : ((s == 1) ? bhh1 : bhh2);
    const float* hw  = (s == 0) ? hw0  : ((s == 1) ? hw1  : hw2);
    const float* hb  = (s == 0) ? hb0  : ((s == 1) ? hb1  : hb2);
    const ushort* wt2s = wt2 + ((s == 0) ? 0u : ((s == 1) ? 393216u : 983040u))
                       + (size_t)j * (s + 2) * 24576;

#define FILLB(SRC, DST) { const uint4* sp_ = (const uint4*)(wt2s + (size_t)(SRC) * 24576); \
    uint4* dp_ = (uint4*)(Blds + (DST) * 24576); \
    _Pragma("unroll") for (int i_ = 0; i_ < 6; i_++) dp_[tid + 512 * i_] = sp_[tid + 512 * i_]; }

    // resident B fill (once)
    if (s == 0)      { FILLB(0, 0) FILLB(1, 1) }
    else if (s == 1) { FILLB(0, 0) FILLB(1, 1) FILLB(2, 2) }
    else             { FILLB(0, 0) FILLB(3, 1) }
    __syncthreads();

    // hoisted per-lane constants (t-invariant)
    float4 G[6];
    #pragma unroll
    for (int ct = 0; ct < 6; ct++)
        G[ct] = ((const float4*)gcf)[(((size_t)(s * 8 + j) * 6 + ct) * 8 + w) * 64 + lane];
    float bhna = bhh[512 + j * 32 + la];
    float bhnb = bhh[512 + j * 32 + 16 + la];
    float hwa0 = hw[j * 32 + la], hwb0 = hw[j * 32 + 16 + la];
    float hwa1 = hw[256 + j * 32 + la], hwb1 = hw[256 + j * 32 + 16 + la];
    float hbi0 = (j == 0) ? hb[0] : 0.f, hbi1 = (j == 0) ? hb[1] : 0.f;
    int* pself = prog + (s * 8 + j) * 16;

#define MCH(REG, AR) { _Pragma("unroll") for (int ks_ = 0; ks_ < 8; ks_++) { \
    const ushort* bb_ = Blds + (REG) * 24576 + ks_ * 512 + lane * 8; \
    bf16x8 a_ = AR[ks_]; \
    acc[0] = __builtin_amdgcn_mfma_f32_16x16x32_bf16(a_, *(const bf16x8*)(bb_        ), acc[0], 0, 0, 0); \
    acc[1] = __builtin_amdgcn_mfma_f32_16x16x32_bf16(a_, *(const bf16x8*)(bb_ +  4096), acc[1], 0, 0, 0); \
    acc[2] = __builtin_amdgcn_mfma_f32_16x16x32_bf16(a_, *(const bf16x8*)(bb_ +  8192), acc[2], 0, 0, 0); \
    acc[3] = __builtin_amdgcn_mfma_f32_16x16x32_bf16(a_, *(const bf16x8*)(bb_ + 12288), acc[3], 0, 0, 0); \
    acc[4] = __builtin_amdgcn_mfma_f32_16x16x32_bf16(a_, *(const bf16x8*)(bb_ + 16384), acc[4], 0, 0, 0); \
    acc[5] = __builtin_amdgcn_mfma_f32_16x16x32_bf16(a_, *(const bf16x8*)(bb_ + 20480), acc[5], 0, 0, 0); } }

#define ISSUE_CB(AR) { const ushort* cs_ = cb + (((size_t)w * 512 + t) << 12); \
    _Pragma("unroll") for (int ks_ = 0; ks_ < 8; ks_++) gld16(AR[ks_], cs_ + ks_ * 512 + lane * 8); }
#define ISSUE_H(AR, P, SLOT) { const ushort* hs_ = hist + ((((size_t)(P) * RS3 + (SLOT)) * 8 + w) << 12); \
    _Pragma("unroll") for (int ks_ = 0; ks_ < 8; ks_++) gld16c(AR[ks_], hs_ + ks_ * 512 + lane * 8); }

    for (int t = 0; t < T_STEPS; ++t) {
        // ---- spins: up to 24 predicated lanes in parallel
        if (tid < 24) {
            int grp = tid >> 3, i8 = tid & 7;
            int want = 0; bool act = false;
            if (s == 0)      { if (grp == 0) { want = t; act = (t > 0); }
                               else          { want = t - RS3 + 1; act = (t >= RS3); } }
            else if (s == 1) { if (grp == 0) { want = t + 1; act = true; }
                               else if (grp == 1) { want = t; act = (t > 0); }
                               else { want = t - RS3 + 1; act = (t >= RS3); } }
            else             { if (grp <= 1) { want = t + 1; act = true; }
                               else { want = t; act = (t > 0); } }
            if (act) {
                int* p = prog + (grp * 8 + i8) * 16;
                while (__hip_atomic_load(p, __ATOMIC_RELAXED, __HIP_MEMORY_SCOPE_AGENT) < want) {}
            }
        }
        __syncthreads();   // B_spin: flags observed; hlds free for rewrite

        f32x4 acc[6];
        #pragma unroll
        for (int ct = 0; ct < 6; ct++) acc[ct] = (f32x4){0.f, 0.f, 0.f, 0.f};

        bf16x8 A0[8], A1[8], A2[8];
        int slot_t  = t & (RS3 - 1);
        int slot_t1 = (t - 1) & (RS3 - 1);

        if (s == 0) {
            ISSUE_CB(A0)
            if (t > 0) { ISSUE_H(A1, 0, slot_t1) VWAIT(8) } else { VWAIT(0) }
            MCH(0, A0)
            if (t > 0) { VWAIT(0) MCH(1, A1) }
        } else if (s == 1) {
            ISSUE_CB(A0)
            ISSUE_H(A1, 0, slot_t)
            if (t > 0) { ISSUE_H(A2, 1, slot_t1) VWAIT(16) } else { VWAIT(8) }
            MCH(0, A0)
            VWAIT(0)
            MCH(1, A1)
            if (t > 0) MCH(2, A2)
        } else {
            // batch 1: B-fill c1 + A c0 + A c1
            uint4 Br[6];
            { const uint4* sp = (const uint4*)(wt2s + (size_t)1 * 24576);
              #pragma unroll
              for (int i = 0; i < 6; i++) gld16u(Br[i], sp + tid + 512 * i); }
            ISSUE_CB(A0)
            ISSUE_H(A1, 0, slot_t)
            VWAIT(8)                      // Bfill(6)+A0(8) done; A1 still in flight
            { uint4* dp = (uint4*)(Blds + 2 * 24576);
              #pragma unroll
              for (int i = 0; i < 6; i++) dp[tid + 512 * i] = Br[i]; }
            MCH(0, A0)
            VWAIT(0)
            __syncthreads();              // Blds[2] = pw-weights visible
            MCH(2, A1)
            // batch 2: B-fill c2 + A c2 + A c3
            { const uint4* sp = (const uint4*)(wt2s + (size_t)2 * 24576);
              #pragma unroll
              for (int i = 0; i < 6; i++) gld16u(Br[i], sp + tid + 512 * i); }
            ISSUE_H(A0, 1, slot_t)
            if (t > 0) ISSUE_H(A1, 2, slot_t1)
            VWAIT(0)
            __syncthreads();              // all waves done reading Blds[2] (c1)
            { uint4* dp = (uint4*)(Blds + 2 * 24576);
              #pragma unroll
              for (int i = 0; i < 6; i++) dp[tid + 512 * i] = Br[i]; }
            __syncthreads();              // Blds[2] = pph-weights visible
            MCH(2, A0)
            if (t > 0) MCH(1, A1)
        }

        // ---- gates fully in-register (C-fragment: lane holds r/z/n for its dims)
        float ha[4], hbv[4];
        #pragma unroll
        for (int q = 0; q < 4; q++) {
            float r1 = sigmoidf_(acc[0][q] + G[0][q]);
            float z1 = sigmoidf_(acc[2][q] + G[2][q]);
            float n1 = tanhf(acc[4][q] + G[4][q] + r1 * bhna);
            ha[q] = (1.0f - z1) * n1;
            float r2 = sigmoidf_(acc[1][q] + G[1][q]);
            float z2 = sigmoidf_(acc[3][q] + G[3][q]);
            float n2 = tanhf(acc[5][q] + G[5][q] + r2 * bhnb);
            hbv[q] = (1.0f - z2) * n2;
        }
        #pragma unroll
        for (int q = 0; q < 4; q++) {
            int smp = w * 16 + ((lane >> 4) << 2) + q;
            hlds[smp * 32 + la]      = f2bf(ha[q]);
            hlds[smp * 32 + 16 + la] = f2bf(hbv[q]);
        }
        __syncthreads();   // B_hlds

        // ---- publish: coalesced write-through to hist fragment slot
        {
            int rt = tid >> 6, rem = tid & 63, r = rem >> 2, oc = rem & 3;
            const ushort* hsp = hlds + (rt * 16 + r) * 32 + oc * 8;
            ull lo = *(const ull*)(hsp);
            ull hi = *(const ull*)(hsp + 4);
            ushort* dst = hist + (((size_t)s * RS3 + slot_t) * 8 + rt) * 4096
                        + j * 512 + (r + 16 * oc) * 8;
            llc_store8(dst, lo);
            llc_store8(dst + 4, hi);
        }
        drain_vmem();
        __syncthreads();   // B_pub: all h at LLC
        if (tid == 0) {
            __hip_atomic_fetch_add(pself, 1, __ATOMIC_RELAXED, __HIP_MEMORY_SCOPE_AGENT);
        }

        // ---- heads (off critical path)
        {
            float y0[4], y1[4];
            #pragma unroll
            for (int q = 0; q < 4; q++) {
                y0[q] = ha[q] * hwa0 + hbv[q] * hwb0;
                y1[q] = ha[q] * hwa1 + hbv[q] * hwb1;
            }
            #pragma unroll
            for (int m = 1; m <= 8; m <<= 1) {
                #pragma unroll
                for (int q = 0; q < 4; q++) {
                    y0[q] += __shfl_xor(y0[q], m);
                    y1[q] += __shfl_xor(y1[q], m);
                }
            }
            if (la == 0) {
                #pragma unroll
                for (int q = 0; q < 4; q++) {
                    int n = w * 16 + ((lane >> 4) << 2) + q;
                    int bi = n >> 3, ci = n & 7;
                    atomicAdd(out + ((size_t)s << 17) + (size_t)((bi * 2 + 0) * 8 + ci) * 512 + t, y0[q] + hbi0);
                    atomicAdd(out + ((size_t)s << 17) + (size_t)((bi * 2 + 1) * 8 + ci) * 512 + t, y1[q] + hbi1);
                }
            }
        }
        drain_vmem();   // clear atomics before next step's counted vmcnt waits
    }
#undef MCH
#undef ISSUE_CB
#undef ISSUE_H
#undef FILLB
}

// ================= legacy fallback (old layouts) =================
__global__ void k_prep(const float* __restrict__ w0, const float* __restrict__ w1,
                       const float* __restrict__ w2, ushort* __restrict__ wt) {
    int idx = blockIdx.x * 256 + threadIdx.x;
    if (idx >= 1769472) return;
    int e, Ks, cols; const float* W;
    if (idx < 393216)      { e = idx;          Ks = 512;  cols = 1024; W = w0; }
    else if (idx < 983040) { e = idx - 393216; Ks = 768;  cols = 1280; W = w1; }
    else                   { e = idx - 983040; Ks = 1024; cols = 1536; W = w2; }
    int c = e / Ks, k = e % Ks;
    int b = c / 96, cc = c % 96, g = cc >> 5, d32 = cc & 31;
    int jr = g * 256 + b * 32 + d32;
    int scol = (k < 256) ? k : (512 + k);
    wt[idx] = f2bf(W[(size_t)jr * cols + scol]);
}

__global__ void k_gconst(const float* __restrict__ w0, const float* __restrict__ w1, const float* __restrict__ w2,
                         const float* __restrict__ bih0, const float* __restrict__ bih1, const float* __restrict__ bih2,
                         const float* __restrict__ bhh0, const float* __restrict__ bhh1, const float* __restrict__ bhh2,
                         const float* __restrict__ sent, const float* __restrict__ ctx,
                         float* __restrict__ gc) {
    int idx = blockIdx.x * 256 + threadIdx.x;
    if (idx >= 3 * 768 * 128) return;
    int n = idx & 127;
    int scc = idx >> 7;
    int c = scc % 768, s = scc / 768;
    const float* W   = (s == 0) ? w0 : ((s == 1) ? w1 : w2);
    const float* bih = (s == 0) ? bih0 : ((s == 1) ? bih1 : bih2);
    const float* bhh = (s == 0) ? bhh0 : ((s == 1) ? bhh1 : bhh2);
    int cols = 1024 + 256 * s;
    int b = c / 96, cc = c % 96, g = cc >> 5, d32 = cc & 31;
    int jr = g * 256 + b * 32 + d32;
    float acc = bih[jr] + ((g < 2) ? bhh[jr] : 0.0f);
    const float4* wr4 = (const float4*)(W + (size_t)jr * cols + 256);
    const float4* sn4 = (const float4*)(sent + (size_t)n * 256);
    const float4* cx4 = (const float4*)(ctx + (size_t)n * 256);
    #pragma unroll 4
    for (int k = 0; k < 64; k++) {
        float4 wv = wr4[k], sv = sn4[k];
        acc += wv.x * sv.x + wv.y * sv.y + wv.z * sv.z + wv.w * sv.w;
    }
    #pragma unroll 4
    for (int k = 0; k < 64; k++) {
        float4 wv = wr4[64 + k], cv = cx4[k];
        acc += wv.x * cv.x + wv.y * cv.y + wv.z * cv.z + wv.w * cv.w;
    }
    gc[(size_t)(s * 128 + n) * 768 + c] = acc;
}

__global__ void __launch_bounds__(128) k_step(
    const float* __restrict__ chars, const ushort* __restrict__ wt,
    const float* __restrict__ gc, ushort* __restrict__ ring,
    const float* __restrict__ bhh0, const float* __restrict__ bhh1, const float* __restrict__ bhh2,
    const float* __restrict__ hw0, const float* __restrict__ hw1, const float* __restrict__ hw2,
    const float* __restrict__ hb0, const float* __restrict__ hb1, const float* __restrict__ hb2,
    float* __restrict__ out, int stepi) {
    __shared__ ushort Alds[16384];
    __shared__ float  glds[16 * GL];

    int bx = blockIdx.x;
    int s  = bx >> 6;
    int r2 = bx & 63;
    int mt = r2 >> 3;
    int nb = r2 & 7;
    int t  = stepi - s;
    if (t < 0 || t >= T_STEPS) return;

    int Ks = 512 + 256 * s;
    const ushort* wts = wt + ((s == 0) ? 0 : ((s == 1) ? 393216 : 983040));
    int tid = threadIdx.x;

    #pragma unroll
    for (int i = 0; i < 4; i++) {
        int q  = tid + 128 * i;
        int r  = q >> 5;
        int ko = (q & 31) << 3;
        int n  = mt * 16 + r;
        const float* src = chars + ((size_t)n * T_STEPS + t) * 256 + ko;
        float4 f0 = *(const float4*)src;
        float4 f1 = *(const float4*)(src + 4);
        union { ushort u[8]; uint4 v; } pk;
        pk.u[0] = f2bf(f0.x); pk.u[1] = f2bf(f0.y); pk.u[2] = f2bf(f0.z); pk.u[3] = f2bf(f0.w);
        pk.u[4] = f2bf(f1.x); pk.u[5] = f2bf(f1.y); pk.u[6] = f2bf(f1.z); pk.u[7] = f2bf(f1.w);
        int pos = (ko >> 5) * 512 + (r + 16 * ((ko >> 3) & 3)) * 8;
        *(uint4*)(Alds + pos) = pk.v;
    }
    int nparts = s + 1;
    for (int p = 0; p < nparts; p++) {
        int slot = (p == s) ? ((t - 1) & 3) : (t & 3);
        const ushort* hsrc = ring + ((size_t)p * 4 + slot) * (128 * 256);
        #pragma unroll
        for (int i = 0; i < 4; i++) {
            int q  = tid + 128 * i;
            int r  = q >> 5;
            int ko = (q & 31) << 3;
            int n  = mt * 16 + r;
            uint4 v = *(const uint4*)(hsrc + (size_t)n * 256 + ko);
            int kg  = 256 + p * 256 + ko;
            int pos = (kg >> 5) * 512 + (r + 16 * ((kg >> 3) & 3)) * 8;
            *(uint4*)(Alds + pos) = v;
        }
    }
    __syncthreads();

    int w = tid >> 6, lane = tid & 63;
    int cbcol = nb * 96 + w * 48;
    f32x4 acc0 = {0,0,0,0}, acc1 = {0,0,0,0}, acc2 = {0,0,0,0};
    const ushort* bp0 = wts + (size_t)(cbcol + (lane & 15)) * Ks + ((lane >> 4) << 3);
    const ushort* bp1 = bp0 + 16 * (size_t)Ks;
    const ushort* bp2 = bp0 + 32 * (size_t)Ks;
    const ushort* ap  = Alds + lane * 8;
    int nk = Ks >> 5;
    #pragma unroll 8
    for (int ks = 0; ks < nk; ks++) {
        bf16x8 a  = *(const bf16x8*)(ap + ks * 512);
        bf16x8 b0 = *(const bf16x8*)(bp0 + ks * 32);
        bf16x8 b1 = *(const bf16x8*)(bp1 + ks * 32);
        bf16x8 b2 = *(const bf16x8*)(bp2 + ks * 32);
        acc0 = __builtin_amdgcn_mfma_f32_16x16x32_bf16(a, b0, acc0, 0, 0, 0);
        acc1 = __builtin_amdgcn_mfma_f32_16x16x32_bf16(a, b1, acc1, 0, 0, 0);
        acc2 = __builtin_amdgcn_mfma_f32_16x16x32_bf16(a, b2, acc2, 0, 0, 0);
    }
    {
        int rbase = (lane >> 4) * 4;
        int c0 = w * 48 + (lane & 15);
        #pragma unroll
        for (int q = 0; q < 4; q++) {
            glds[(rbase + q) * GL + c0]      = acc0[q];
            glds[(rbase + q) * GL + c0 + 16] = acc1[q];
            glds[(rbase + q) * GL + c0 + 32] = acc2[q];
        }
    }
    __syncthreads();

    {
        int sl = tid >> 3;
        int d0 = (tid & 7) * 4;
        int n  = mt * 16 + sl;
        const float* bhh = (s == 0) ? bhh0 : ((s == 1) ? bhh1 : bhh2);
        const float* hw  = (s == 0) ? hw0  : ((s == 1) ? hw1  : hw2);
        const float* hb  = (s == 0) ? hb0  : ((s == 1) ? hb1  : hb2);
        const float* gcp = gc + (size_t)(s * 128 + n) * 768 + nb * 96;
        float y0 = 0.f, y1 = 0.f;
        union { ushort u[4]; uint2 v; } hpk;
        #pragma unroll
        for (int dd = 0; dd < 4; dd++) {
            int d32 = d0 + dd;
            int d   = nb * 32 + d32;
            float rp = glds[sl * GL + d32]      + gcp[d32];
            float zp = glds[sl * GL + 32 + d32] + gcp[32 + d32];
            float np = glds[sl * GL + 64 + d32] + gcp[64 + d32];
            float rg = sigmoidf_(rp);
            float zg = sigmoidf_(zp);
            float ng = tanhf(np + rg * bhh[512 + d]);
            float h  = (1.0f - zg) * ng;
            hpk.u[dd] = f2bf(h);
            y0 += h * hw[d];
            y1 += h * hw[256 + d];
        }
        *(uint2*)(ring + (((size_t)s * 4 + (t & 3)) * 128 + n) * 256 + nb * 32 + d0) = hpk.v;
        y0 += __shfl_xor(y0, 1); y0 += __shfl_xor(y0, 2); y0 += __shfl_xor(y0, 4);
        y1 += __shfl_xor(y1, 1); y1 += __shfl_xor(y1, 2); y1 += __shfl_xor(y1, 4);
        if ((tid & 7) == 0) {
            if (nb == 0) { y0 += hb[0]; y1 += hb[1]; }
            int bi = n >> 3, ci = n & 7;
            atomicAdd(out + (size_t)s * 131072 + (size_t)((bi * 2 + 0) * 8 + ci) * 512 + t, y0);
            atomicAdd(out + (size_t)s * 131072 + (size_t)((bi * 2 + 1) * 8 + ci) * 512 + t, y1);
        }
    }
}

extern "C" void kernel_launch(void* const* d_in, const int* in_sizes, int n_in,
                              void* d_out, int out_size, void* d_ws, size_t ws_size,
                              hipStream_t stream) {
    const float* chars = (const float*)d_in[0];
    const float* sent  = (const float*)d_in[1];
    const float* ctx   = (const float*)d_in[2];
    const float* w0    = (const float*)d_in[3];
    const float* bih0  = (const float*)d_in[4];
    const float* bhh0  = (const float*)d_in[5];
    const float* w1    = (const float*)d_in[6];
    const float* bih1  = (const float*)d_in[7];
    const float* bhh1  = (const float*)d_in[8];
    const float* w2    = (const float*)d_in[9];
    const float* bih2  = (const float*)d_in[10];
    const float* bhh2  = (const float*)d_in[11];
    const float* hw0   = (const float*)d_in[12];
    const float* hb0   = (const float*)d_in[13];
    const float* hw1   = (const float*)d_in[14];
    const float* hb1   = (const float*)d_in[15];
    const float* hw2   = (const float*)d_in[16];
    const float* hb2   = (const float*)d_in[17];

    char* ws = (char*)d_ws;
    float* out = (float*)d_out;

    hipMemsetAsync(d_out, 0, (size_t)out_size * sizeof(float), stream);

    if (ws_size >= NEED_NEW) {
        ushort* wt2  = (ushort*)(ws + WT_OFF);
        float*  gcf  = (float*)(ws + GC_OFF);
        int*    prg  = (int*)(ws + PROG_OFF);
        ushort* hist = (ushort*)(ws + HIST3_OFF);
        ushort* cbuf = (ushort*)(ws + CB_OFF);
        hipMemsetAsync(ws + PROG_OFF, 0, 4096, stream);
        k_prep2<<<6912, 256, 0, stream>>>(w0, w1, w2, wt2);
        k_gconst2<<<1152, 256, 0, stream>>>(w0, w1, w2, bih0, bih1, bih2,
                                            bhh0, bhh1, bhh2, sent, ctx, gcf);
        k_cprep<<<8192, 256, 0, stream>>>(chars, cbuf);
        k_run3<<<24, 512, 0, stream>>>(cbuf, wt2, gcf, hist, prg,
                                       bhh0, bhh1, bhh2, hw0, hw1, hw2,
                                       hb0, hb1, hb2, out);
    } else {
        ushort* wt  = (ushort*)(ws + WT_OFF);
        float*  gcb = (float*)(ws + GC_OFF);
        ushort* ring = (ushort*)(ws + RING_OFF);
        k_prep<<<6912, 256, 0, stream>>>(w0, w1, w2, wt);
        k_gconst<<<1152, 256, 0, stream>>>(w0, w1, w2, bih0, bih1, bih2,
                                           bhh0, bhh1, bhh2, sent, ctx, gcb);
        hipMemsetAsync(ring, 0, (size_t)3 * 4 * 128 * 256 * 2, stream);
        for (int i = 0; i < T_STEPS + 2; i++) {
            k_step<<<192, 128, 0, stream>>>(chars, wt, gcb, ring,
                                            bhh0, bhh1, bhh2, hw0, hw1, hw2,
                                            hb0, hb1, hb2, out, i);
        }
    }
}